// Round 7
// baseline (265.341 us; speedup 1.0000x reference)
//
#include <hip/hip_runtime.h>
#include <hip/hip_bf16.h>
#include <math.h>

#define Bn 16
#define Cn 32
#define Hn 128
#define Wn 128
#define HW (Hn*Wn)
#define Rn 8
#define OUTn 32
#define PW 130           // padded width/height (1-px halo)

// ws layout (byte offsets, all 16B-aligned)
#define OFF_POOLED 0u            // 4608 f (pool SUMS, scaled in g_kernel)
#define OFF_G      18432u        // 9216 f
#define OFF_KERNA  55296u        // 1179648 bf16  A-frag layout [b][r][t*2+h][kg][m][j]
#define OFF_WFA    2414592u      // 18432 bf16    A-frag layout [kb*2+h][kg][m][j]
#define OFF_RSEL   2451456u      // 262144 int
#define OFF_INTP   3500032u      // 16*16900 px * 64B  bf16 channel-last, padded
#define OFF_CATP   20805632u     // 16*16900 px * 128B bf16 channel-last, padded
// ends 55,416,832

typedef __attribute__((ext_vector_type(8))) short short8;
typedef __attribute__((ext_vector_type(4))) float floatx4;

static __device__ __forceinline__ unsigned short f2b(float f) {
  __hip_bfloat16 h = __float2bfloat16(f);
  return *reinterpret_cast<unsigned short*>(&h);
}

// ---------------- stage A: dynamic kernel generation ----------------

// g_kernel now scales pool SUMS by 1/n (pool fused into tr_kernel)
__global__ void g_kernel(const float* __restrict__ poolsum, const float* __restrict__ w1,
                         const float* __restrict__ b1, float* __restrict__ g) {
  const int idx = blockIdx.x * 256 + threadIdx.x;   // (b*64 + o64)*9 + bin
  if (idx >= Bn * 64 * 9) return;
  const int bin = idx % 9;
  const int o = (idx / 9) % 64;
  const int b = idx / (9 * 64);
  const int bi = bin / 3, bj = bin % 3;
  const float szr[3] = {43.f, 44.f, 43.f};
  const float invn = 1.f / (szr[bi] * szr[bj]);
  float acc = b1[o];
  #pragma unroll
  for (int c = 0; c < Cn; ++c)
    acc = fmaf(poolsum[(b * Cn + c) * 9 + bin] * invn, w1[o * Cn + c], acc);
  g[idx] = 1.f / (1.f + expf(-acc));
}

// kernA: per (b,r): 18 fragments (t*2+h), each [kg(4)][m(16)][j(8)] bf16.
__global__ void kern_kernel(const float* __restrict__ g, const float* __restrict__ w2,
                            const float* __restrict__ b2, short* __restrict__ kernA) {
  const int idx = blockIdx.x * 256 + threadIdx.x;
  if (idx >= Bn * 8 * 9 * 1024) return;
  const int j  = idx & 7;
  const int m  = (idx >> 3) & 15;
  const int kg = (idx >> 7) & 3;
  const int h  = (idx >> 9) & 1;
  const int t  = (idx >> 10) % 9;
  const int br = idx / 9216;
  const int r = br & 7, b = br >> 3;
  const int c = kg * 8 + j;
  const int u = h * 16 + m;
  const int jidx = u * 32 + c;                     // index within C*OUT group
  float acc = b2[r * 1024 + jidx];
  #pragma unroll
  for (int i = 0; i < 8; ++i)
    acc = fmaf(g[(b * 64 + r * 8 + i) * 9 + t], w2[(r * 1024 + jidx) * 8 + i], acc);
  kernA[idx] = (short)f2b(acc);
}

// wfA: 18 K-blocks (kb = tap*2+chalf) x 2 o-halves, each [kg][m][j] bf16.
__global__ void wf_kernel(const float* __restrict__ w_f, short* __restrict__ wfA) {
  int idx = blockIdx.x * 256 + threadIdx.x;
  if (idx >= 18432) return;
  const int j  = idx & 7;
  const int m  = (idx >> 3) & 15;
  const int kg = (idx >> 7) & 3;
  const int h  = (idx >> 9) & 1;
  const int kb = idx >> 10;        // 0..17
  const int tap = kb >> 1, ch = kb & 1;
  const int ci = ch * 32 + kg * 8 + j;
  const int o = h * 16 + m;
  wfA[idx] = (short)f2b(w_f[(o * 64 + ci) * 9 + tap]);
}

// ---------------- halo zero + poolsum zero ----------------

__global__ void halo_kernel(uint4* __restrict__ inTp, uint4* __restrict__ catp,
                            float* __restrict__ poolsum) {
  const int idx = blockIdx.x * 256 + threadIdx.x;   // b*520 + i
  if (idx < Bn * Cn * 9) poolsum[idx] = 0.f;
  if (idx >= Bn * 520) return;
  const int b = idx / 520, i = idx % 520;
  int y, x;
  if (i < 130)      { y = 0;       x = i; }
  else if (i < 260) { y = 129;     x = i - 130; }
  else if (i < 390) { y = i - 260; x = 0; }
  else              { y = i - 390; x = 129; }
  const size_t pp = (size_t)(b * PW + y) * PW + x;
  const uint4 z = make_uint4(0u, 0u, 0u, 0u);
  #pragma unroll
  for (int q = 0; q < 4; ++q) inTp[pp * 4 + q] = z;
  #pragma unroll
  for (int q = 0; q < 8; ++q) catp[pp * 8 + q] = z;
}

// ---------------- input transpose to padded channel-last bf16 + fused pool ----------------

__global__ __launch_bounds__(256) void tr_kernel(const float* __restrict__ in,
                                                 uint4* __restrict__ inTp,
                                                 float* __restrict__ poolsum) {
  __shared__ float lds[32][65];
  const int blk = blockIdx.x;          // b*256 + pixel-group
  const int b = blk >> 8;
  const int p0 = (blk & 255) * 64;
  const int tid = threadIdx.x;
  const int pl = tid & 63;
  const int c0 = tid >> 6;             // 0..3
  #pragma unroll
  for (int cc = 0; cc < 8; ++cc) {
    const int c = cc * 4 + c0;
    lds[c][pl] = in[(size_t)(b * 32 + c) * HW + p0 + pl];
  }
  __syncthreads();
  {
    const int pw = tid >> 2;             // 0..63
    const int cg = (tid & 3) * 8;        // 0,8,16,24
    unsigned int w0 = (unsigned)f2b(lds[cg + 0][pw]) | ((unsigned)f2b(lds[cg + 1][pw]) << 16);
    unsigned int w1 = (unsigned)f2b(lds[cg + 2][pw]) | ((unsigned)f2b(lds[cg + 3][pw]) << 16);
    unsigned int w2 = (unsigned)f2b(lds[cg + 4][pw]) | ((unsigned)f2b(lds[cg + 5][pw]) << 16);
    unsigned int w3 = (unsigned)f2b(lds[cg + 6][pw]) | ((unsigned)f2b(lds[cg + 7][pw]) << 16);
    const int p = p0 + pw;
    const int y = p >> 7, x = p & 127;
    const size_t pp = (size_t)(b * PW + y + 1) * PW + (x + 1);
    inTp[pp * 4 + (tid & 3)] = make_uint4(w0, w1, w2, w3);
  }
  // fused adaptive-pool partial sums. Bins overlap: row/col 42 is in bins 0&1,
  // row/col 85 in bins 1&2 (torch adaptive_avg_pool2d edges for 128/3).
  const int x0 = p0 & 127;             // 0 or 64 (block spans half a row)
  const int y  = p0 >> 7;
  const int c  = tid >> 3, j = tid & 7;
  const int plo = j * 8;
  const int splitA = x0 ? 22 : 43;     // pl <  splitA -> binA
  const int splitB = x0 ? 21 : 42;     // pl >= splitB -> binB
  float sumA = 0.f, sumB = 0.f;
  #pragma unroll
  for (int k = 0; k < 8; ++k) {
    const float v = lds[c][plo + k];
    if (plo + k < splitA)  sumA += v;
    if (plo + k >= splitB) sumB += v;
  }
  sumA += __shfl_down(sumA, 4, 64); sumB += __shfl_down(sumB, 4, 64);
  sumA += __shfl_down(sumA, 2, 64); sumB += __shfl_down(sumB, 2, 64);
  sumA += __shfl_down(sumA, 1, 64); sumB += __shfl_down(sumB, 1, 64);
  if (j == 0) {
    const int bi0 = (y < 43) ? 0 : ((y < 86) ? 1 : 2);
    const int bi1 = (y == 42) ? 1 : ((y == 85) ? 2 : -1);
    const int bjA = x0 ? 1 : 0, bjB = x0 ? 2 : 1;
    float* ps = poolsum + (b * Cn + c) * 9;
    atomicAdd(ps + bi0 * 3 + bjA, sumA);
    atomicAdd(ps + bi0 * 3 + bjB, sumB);
    if (bi1 >= 0) {
      atomicAdd(ps + bi1 * 3 + bjA, sumA);
      atomicAdd(ps + bi1 * 3 + bjB, sumB);
    }
  }
}

// ---------------- region selection ----------------

__global__ void rsel_kernel(const float* __restrict__ guide,
                            const float* __restrict__ w_spa, const float* __restrict__ b_spa,
                            const float* __restrict__ w_spec, const float* __restrict__ b_spec,
                            int* __restrict__ rsel) {
  const int idx = blockIdx.x * 256 + threadIdx.x;   // b*HW + p
  const int b = idx >> 14;
  const int p = idx & (HW - 1);
  float gv[Cn];
  const float* gp = guide + (size_t)b * Cn * HW + p;
  #pragma unroll
  for (int c = 0; c < Cn; ++c) gv[c] = gp[c * HW];
  int best1 = 0, best2 = 0;
  float bv1 = -1e30f, bv2 = -1e30f;
  for (int r = 0; r < Rn; ++r) {
    float v1 = b_spa[r], v2 = b_spec[r];
    #pragma unroll
    for (int c = 0; c < Cn; ++c) {
      v1 = fmaf(gv[c], w_spa[r * Cn + c], v1);
      v2 = fmaf(gv[c], w_spec[r * Cn + c], v2);
    }
    if (v1 > bv1) { bv1 = v1; best1 = r; }   // strict > keeps FIRST max (jnp.argmax)
    if (v2 > bv2) { bv2 = v2; best2 = r; }
  }
  rsel[idx] = best1 | (best2 << 8);
}

// ---------------- stage B: selected correlation conv via MFMA ----------------
// C[o(32), entry(16)] per group; A = generated weights, B = input pixels.
// All 9 tap loads issued before the MFMA chain (9 in flight per wave).

__global__ void stageB_kernel(
    const char* __restrict__ inTp, const short* __restrict__ kernA,
    const int* __restrict__ rsel, char* __restrict__ catp) {
  const int id = blockIdx.x;
  const int chunk = id & 7, r = (id >> 3) & 7, b = id >> 6;  // chunk fastest -> XCD affinity
  const int pbase = chunk * 2048;
  __shared__ int lcount;
  __shared__ unsigned short list[4096];
  const int tid = threadIdx.x;
  if (tid == 0) lcount = 0;
  __syncthreads();
  const int* rs = rsel + b * HW + pbase;
  for (int i = tid; i < 2048; i += 256) {
    int v = rs[i];
    if ((v & 255) == r) { int k = atomicAdd(&lcount, 1); list[k] = (unsigned short)i; }
    if ((v >> 8) == r)  { int k = atomicAdd(&lcount, 1); list[k] = (unsigned short)(i | 2048); }
  }
  __syncthreads();
  const int cnt = lcount;
  const int lane = tid & 63, wid = tid >> 6;
  const int l15 = lane & 15, kg = lane >> 4;

  // preload the 18 weight A-fragments (uniform per block)
  short8 aw[18];
  {
    const short* kb = kernA + (size_t)(b * 8 + r) * 18 * 512;
    #pragma unroll
    for (int f = 0; f < 18; ++f)
      aw[f] = *(const short8*)(kb + f * 512 + kg * 128 + l15 * 8);
  }

  for (int g = wid; g * 16 < cnt; g += 4) {
    const int e16 = g * 16 + l15;
    const bool ev = e16 < cnt;
    const int ent = list[ev ? e16 : 0];
    const int p = pbase + (ent & 2047);
    const int which = ent >> 11;
    const int y = p >> 7, x = p & 127;
    const size_t pp = (size_t)(b * PW + y + 1) * PW + (x + 1);
    const char* base = inTp + pp * 64 + kg * 16;
    short8 bx[9];
    #pragma unroll
    for (int t = 0; t < 9; ++t) {
      const int dy = t / 3 - 1, dx = t % 3 - 1;
      bx[t] = *(const short8*)(base + (dy * PW + dx) * 64);
    }
    floatx4 acc0 = {0.f, 0.f, 0.f, 0.f}, acc1 = {0.f, 0.f, 0.f, 0.f};
    #pragma unroll
    for (int t = 0; t < 9; ++t) {
      acc0 = __builtin_amdgcn_mfma_f32_16x16x32_bf16(aw[t * 2 + 0], bx[t], acc0, 0, 0, 0);
      acc1 = __builtin_amdgcn_mfma_f32_16x16x32_bf16(aw[t * 2 + 1], bx[t], acc1, 0, 0, 0);
    }
    if (ev) {
      char* op = catp + pp * 128 + which * 64 + kg * 8;
      uint2 v0, v1;
      v0.x = (unsigned)f2b(acc0[0]) | ((unsigned)f2b(acc0[1]) << 16);
      v0.y = (unsigned)f2b(acc0[2]) | ((unsigned)f2b(acc0[3]) << 16);
      v1.x = (unsigned)f2b(acc1[0]) | ((unsigned)f2b(acc1[1]) << 16);
      v1.y = (unsigned)f2b(acc1[2]) | ((unsigned)f2b(acc1[3]) << 16);
      *(uint2*)op = v0;
      *(uint2*)(op + 32) = v1;
    }
  }
}

// ---------------- stage C: fusion conv via MFMA + bias + residual ----------------
// XCD-chunked swizzle (T1) + explicit 2-stage load/MFMA software pipeline:
// LOADTAP issues 8 b128 loads for tap t+1 while MFMATAP retires 16 MFMAs of tap t.

__global__ __launch_bounds__(256, 4) void stageC_kernel(
    const char* __restrict__ catp, const short* __restrict__ wfA,
    const float* __restrict__ b_f, const float* __restrict__ in,
    float* __restrict__ out) {
  __shared__ short lwf[18432];
  const int tid = threadIdx.x;
  {
    const uint4* src = (const uint4*)wfA;
    uint4* dst = (uint4*)lwf;
    #pragma unroll
    for (int i = 0; i < 9; ++i)
      dst[i * 256 + tid] = src[i * 256 + tid];
  }
  __syncthreads();
  const int id = (blockIdx.x & 7) * 128 + (blockIdx.x >> 3);   // T1 XCD swizzle
  const int b = id >> 6, seg = id & 63;
  const int lane = tid & 63, wid = tid >> 6;
  const int l15 = lane & 15, kg = lane >> 4;
  const int pix = seg * 256 + wid * 64 + l15;     // + q*16

  const char* bq[4];
  #pragma unroll
  for (int q = 0; q < 4; ++q) {
    const int p = pix + q * 16;
    const int y = p >> 7, x = p & 127;
    bq[q] = catp + ((size_t)(b * PW + y + 1) * PW + (x + 1)) * 128 + kg * 16;
  }
  floatx4 acc[2][4] = {};
  short8 bxA[8], bxB[8];

#define GOFF(T) (((((T) / 3) - 1) * PW + (((T) % 3) - 1)) * 128)

#define LOADTAP(BUF, T)                                              \
  { _Pragma("unroll")                                                \
    for (int q = 0; q < 4; ++q) {                                    \
      BUF[q * 2 + 0] = *(const short8*)(bq[q] + GOFF(T));            \
      BUF[q * 2 + 1] = *(const short8*)(bq[q] + GOFF(T) + 64);       \
    } }

#define MFMATAP(BUF, T)                                                              \
  { const short8 a00 = *(const short8*)&lwf[(4*(T)+0)*512 + kg*128 + l15*8];          \
    const short8 a01 = *(const short8*)&lwf[(4*(T)+1)*512 + kg*128 + l15*8];          \
    const short8 a10 = *(const short8*)&lwf[(4*(T)+2)*512 + kg*128 + l15*8];          \
    const short8 a11 = *(const short8*)&lwf[(4*(T)+3)*512 + kg*128 + l15*8];          \
    _Pragma("unroll")                                                                 \
    for (int q = 0; q < 4; ++q) {                                                     \
      acc[0][q] = __builtin_amdgcn_mfma_f32_16x16x32_bf16(a00, BUF[q*2+0], acc[0][q], 0, 0, 0); \
      acc[1][q] = __builtin_amdgcn_mfma_f32_16x16x32_bf16(a01, BUF[q*2+0], acc[1][q], 0, 0, 0); \
      acc[0][q] = __builtin_amdgcn_mfma_f32_16x16x32_bf16(a10, BUF[q*2+1], acc[0][q], 0, 0, 0); \
      acc[1][q] = __builtin_amdgcn_mfma_f32_16x16x32_bf16(a11, BUF[q*2+1], acc[1][q], 0, 0, 0); \
    } }

  LOADTAP(bxA, 0)
  LOADTAP(bxB, 1)  MFMATAP(bxA, 0)
  LOADTAP(bxA, 2)  MFMATAP(bxB, 1)
  LOADTAP(bxB, 3)  MFMATAP(bxA, 2)
  LOADTAP(bxA, 4)  MFMATAP(bxB, 3)
  LOADTAP(bxB, 5)  MFMATAP(bxA, 4)
  LOADTAP(bxA, 6)  MFMATAP(bxB, 5)
  LOADTAP(bxB, 7)  MFMATAP(bxA, 6)
  LOADTAP(bxA, 8)  MFMATAP(bxB, 7)
                   MFMATAP(bxA, 8)
#undef LOADTAP
#undef MFMATAP
#undef GOFF

  #pragma unroll
  for (int h = 0; h < 2; ++h) {
    const int o0 = h * 16 + kg * 4;
    #pragma unroll
    for (int q = 0; q < 4; ++q) {
      const int p = pix + q * 16;
      #pragma unroll
      for (int reg = 0; reg < 4; ++reg) {
        const size_t oi = (size_t)(b * 32 + o0 + reg) * HW + p;
        out[oi] = acc[h][q][reg] + b_f[o0 + reg] + in[oi];
      }
    }
  }
}

// ---------------- launcher ----------------

extern "C" void kernel_launch(void* const* d_in, const int* in_sizes, int n_in,
                              void* d_out, int out_size, void* d_ws, size_t ws_size,
                              hipStream_t stream) {
  const float* input  = (const float*)d_in[0];
  const float* guide  = (const float*)d_in[1];
  const float* w1     = (const float*)d_in[2];
  const float* b1     = (const float*)d_in[3];
  const float* w2     = (const float*)d_in[4];
  const float* b2     = (const float*)d_in[5];
  const float* w_spa  = (const float*)d_in[6];
  const float* b_spa  = (const float*)d_in[7];
  const float* w_spec = (const float*)d_in[8];
  const float* b_spec = (const float*)d_in[9];
  const float* w_f    = (const float*)d_in[10];
  const float* b_f    = (const float*)d_in[11];
  float* out = (float*)d_out;

  char* ws = (char*)d_ws;
  float* poolsum = (float*)(ws + OFF_POOLED);
  float* g      = (float*)(ws + OFF_G);
  short* kernA  = (short*)(ws + OFF_KERNA);
  short* wfA    = (short*)(ws + OFF_WFA);
  int*   rsel   = (int*)(ws + OFF_RSEL);
  uint4* inTp   = (uint4*)(ws + OFF_INTP);
  char*  catp   = (char*)(ws + OFF_CATP);

  wf_kernel<<<72, 256, 0, stream>>>(w_f, wfA);
  halo_kernel<<<(Bn * 520 + 255) / 256, 256, 0, stream>>>(inTp, (uint4*)catp, poolsum);
  tr_kernel<<<Bn * 256, 256, 0, stream>>>(input, inTp, poolsum);
  g_kernel<<<(Bn * 64 * 9 + 255) / 256, 256, 0, stream>>>(poolsum, w1, b1, g);
  kern_kernel<<<Bn * 8 * 9 * 1024 / 256, 256, 0, stream>>>(g, w2, b2, kernA);
  rsel_kernel<<<Bn * HW / 256, 256, 0, stream>>>(guide, w_spa, b_spa, w_spec, b_spec, rsel);
  stageB_kernel<<<1024, 256, 0, stream>>>((const char*)inTp, kernA, rsel, catp);
  stageC_kernel<<<1024, 256, 0, stream>>>(catp, wfA, b_f, input, out);
}

// Round 8
// 263.954 us; speedup vs baseline: 1.0053x; 1.0053x over previous
//
#include <hip/hip_runtime.h>
#include <hip/hip_bf16.h>
#include <math.h>

#define Bn 16
#define Cn 32
#define Hn 128
#define Wn 128
#define HW (Hn*Wn)
#define Rn 8
#define OUTn 32
#define PW 130           // padded width/height (1-px halo)

// ws layout (byte offsets, all 16B-aligned)
#define OFF_POOLED 0u            // 4608 f (pool SUMS, scaled in g_kernel)
#define OFF_G      18432u        // 9216 f
#define OFF_KERNA  55296u        // 1179648 bf16  A-frag layout [b][r][t*2+h][kg][m][j]
#define OFF_WFA    2414592u      // 18432 bf16    A-frag layout [kb*2+h][kg][m][j]
#define OFF_RSEL   2451456u      // 262144 int
#define OFF_INTP   3500032u      // 16*16900 px * 64B  bf16 channel-last, padded
#define OFF_CATP   20805632u     // 16*16900 px * 128B bf16 channel-last, padded
// ends 55,416,832

typedef __attribute__((ext_vector_type(8))) short short8;
typedef __attribute__((ext_vector_type(4))) float floatx4;

static __device__ __forceinline__ unsigned short f2b(float f) {
  __hip_bfloat16 h = __float2bfloat16(f);
  return *reinterpret_cast<unsigned short*>(&h);
}

// ---------------- stage A: dynamic kernel generation ----------------

// g_kernel scales pool SUMS by 1/n (pool fused into tr_kernel)
__global__ void g_kernel(const float* __restrict__ poolsum, const float* __restrict__ w1,
                         const float* __restrict__ b1, float* __restrict__ g) {
  const int idx = blockIdx.x * 256 + threadIdx.x;   // (b*64 + o64)*9 + bin
  if (idx >= Bn * 64 * 9) return;
  const int bin = idx % 9;
  const int o = (idx / 9) % 64;
  const int b = idx / (9 * 64);
  const int bi = bin / 3, bj = bin % 3;
  const float szr[3] = {43.f, 44.f, 43.f};
  const float invn = 1.f / (szr[bi] * szr[bj]);
  float acc = b1[o];
  #pragma unroll
  for (int c = 0; c < Cn; ++c)
    acc = fmaf(poolsum[(b * Cn + c) * 9 + bin] * invn, w1[o * Cn + c], acc);
  g[idx] = 1.f / (1.f + expf(-acc));
}

// kernA: per (b,r): 18 fragments (t*2+h), each [kg(4)][m(16)][j(8)] bf16.
__global__ void kern_kernel(const float* __restrict__ g, const float* __restrict__ w2,
                            const float* __restrict__ b2, short* __restrict__ kernA) {
  const int idx = blockIdx.x * 256 + threadIdx.x;
  if (idx >= Bn * 8 * 9 * 1024) return;
  const int j  = idx & 7;
  const int m  = (idx >> 3) & 15;
  const int kg = (idx >> 7) & 3;
  const int h  = (idx >> 9) & 1;
  const int t  = (idx >> 10) % 9;
  const int br = idx / 9216;
  const int r = br & 7, b = br >> 3;
  const int c = kg * 8 + j;
  const int u = h * 16 + m;
  const int jidx = u * 32 + c;                     // index within C*OUT group
  float acc = b2[r * 1024 + jidx];
  #pragma unroll
  for (int i = 0; i < 8; ++i)
    acc = fmaf(g[(b * 64 + r * 8 + i) * 9 + t], w2[(r * 1024 + jidx) * 8 + i], acc);
  kernA[idx] = (short)f2b(acc);
}

// wfA: 18 K-blocks (kb = tap*2+chalf) x 2 o-halves, each [kg][m][j] bf16.
// Also zeroes poolsum (must run before tr_kernel's atomics).
__global__ void wf_kernel(const float* __restrict__ w_f, short* __restrict__ wfA,
                          float* __restrict__ poolsum) {
  int idx = blockIdx.x * 256 + threadIdx.x;
  if (idx < Bn * Cn * 9) poolsum[idx] = 0.f;
  if (idx >= 18432) return;
  const int j  = idx & 7;
  const int m  = (idx >> 3) & 15;
  const int kg = (idx >> 7) & 3;
  const int h  = (idx >> 9) & 1;
  const int kb = idx >> 10;        // 0..17
  const int tap = kb >> 1, ch = kb & 1;
  const int ci = ch * 32 + kg * 8 + j;
  const int o = h * 16 + m;
  wfA[idx] = (short)f2b(w_f[(o * 64 + ci) * 9 + tap]);
}

// ---------------- input transpose to padded channel-last bf16 + fused pool ----------------

__global__ __launch_bounds__(256) void tr_kernel(const float* __restrict__ in,
                                                 uint4* __restrict__ inTp,
                                                 float* __restrict__ poolsum) {
  __shared__ float lds[32][65];
  const int blk = blockIdx.x;          // b*256 + pixel-group
  const int b = blk >> 8;
  const int p0 = (blk & 255) * 64;
  const int tid = threadIdx.x;
  const int pl = tid & 63;
  const int c0 = tid >> 6;             // 0..3
  #pragma unroll
  for (int cc = 0; cc < 8; ++cc) {
    const int c = cc * 4 + c0;
    lds[c][pl] = in[(size_t)(b * 32 + c) * HW + p0 + pl];
  }
  __syncthreads();
  {
    const int pw = tid >> 2;             // 0..63
    const int cg = (tid & 3) * 8;        // 0,8,16,24
    unsigned int w0 = (unsigned)f2b(lds[cg + 0][pw]) | ((unsigned)f2b(lds[cg + 1][pw]) << 16);
    unsigned int w1 = (unsigned)f2b(lds[cg + 2][pw]) | ((unsigned)f2b(lds[cg + 3][pw]) << 16);
    unsigned int w2 = (unsigned)f2b(lds[cg + 4][pw]) | ((unsigned)f2b(lds[cg + 5][pw]) << 16);
    unsigned int w3 = (unsigned)f2b(lds[cg + 6][pw]) | ((unsigned)f2b(lds[cg + 7][pw]) << 16);
    const int p = p0 + pw;
    const int y = p >> 7, x = p & 127;
    const size_t pp = (size_t)(b * PW + y + 1) * PW + (x + 1);
    inTp[pp * 4 + (tid & 3)] = make_uint4(w0, w1, w2, w3);
  }
  // fused adaptive-pool partial sums. Bins overlap: row/col 42 in bins 0&1,
  // row/col 85 in bins 1&2 (torch adaptive_avg_pool2d edges for 128/3).
  const int x0 = p0 & 127;             // 0 or 64 (block spans half a row)
  const int y  = p0 >> 7;
  const int c  = tid >> 3, j = tid & 7;
  const int plo = j * 8;
  const int splitA = x0 ? 22 : 43;     // pl <  splitA -> binA
  const int splitB = x0 ? 21 : 42;     // pl >= splitB -> binB
  float sumA = 0.f, sumB = 0.f;
  #pragma unroll
  for (int k = 0; k < 8; ++k) {
    const float v = lds[c][plo + k];
    if (plo + k < splitA)  sumA += v;
    if (plo + k >= splitB) sumB += v;
  }
  sumA += __shfl_down(sumA, 4, 64); sumB += __shfl_down(sumB, 4, 64);
  sumA += __shfl_down(sumA, 2, 64); sumB += __shfl_down(sumB, 2, 64);
  sumA += __shfl_down(sumA, 1, 64); sumB += __shfl_down(sumB, 1, 64);
  if (j == 0) {
    const int bi0 = (y < 43) ? 0 : ((y < 86) ? 1 : 2);
    const int bi1 = (y == 42) ? 1 : ((y == 85) ? 2 : -1);
    const int bjA = x0 ? 1 : 0, bjB = x0 ? 2 : 1;
    float* ps = poolsum + (b * Cn + c) * 9;
    atomicAdd(ps + bi0 * 3 + bjA, sumA);
    atomicAdd(ps + bi0 * 3 + bjB, sumB);
    if (bi1 >= 0) {
      atomicAdd(ps + bi1 * 3 + bjA, sumA);
      atomicAdd(ps + bi1 * 3 + bjB, sumB);
    }
  }
}

// ---------------- region selection (LDS-staged coalesced) + halo zero ----------------

__global__ __launch_bounds__(256) void rsel_kernel(
    const float* __restrict__ guide,
    const float* __restrict__ w_spa, const float* __restrict__ b_spa,
    const float* __restrict__ w_spec, const float* __restrict__ b_spec,
    int* __restrict__ rsel, uint4* __restrict__ inTp, uint4* __restrict__ catp) {
  const int tid = threadIdx.x;
  // side-job: halo zero (runs in first 33 blocks; complete before stageB/stageC)
  {
    const int hidx = blockIdx.x * 256 + tid;
    if (hidx < Bn * 520) {
      const int hb = hidx / 520, i = hidx % 520;
      int y, x;
      if (i < 130)      { y = 0;       x = i; }
      else if (i < 260) { y = 129;     x = i - 130; }
      else if (i < 390) { y = i - 260; x = 0; }
      else              { y = i - 390; x = 129; }
      const size_t pp = (size_t)(hb * PW + y) * PW + x;
      const uint4 z = make_uint4(0u, 0u, 0u, 0u);
      #pragma unroll
      for (int q = 0; q < 4; ++q) inTp[pp * 4 + q] = z;
      #pragma unroll
      for (int q = 0; q < 8; ++q) catp[pp * 8 + q] = z;
    }
  }
  __shared__ float lds[32][256];
  const int b = blockIdx.x >> 6;
  const int p0 = (blockIdx.x & 63) * 256;
  const float* gp = guide + (size_t)b * Cn * HW + p0;
  #pragma unroll
  for (int c = 0; c < Cn; ++c)
    lds[c][tid] = gp[(size_t)c * HW + tid];
  __syncthreads();
  float gv[Cn];
  #pragma unroll
  for (int c = 0; c < Cn; ++c) gv[c] = lds[c][tid];
  int best1 = 0, best2 = 0;
  float bv1 = -1e30f, bv2 = -1e30f;
  for (int r = 0; r < Rn; ++r) {
    float v1 = b_spa[r], v2 = b_spec[r];
    #pragma unroll
    for (int c = 0; c < Cn; ++c) {
      v1 = fmaf(gv[c], w_spa[r * Cn + c], v1);
      v2 = fmaf(gv[c], w_spec[r * Cn + c], v2);
    }
    if (v1 > bv1) { bv1 = v1; best1 = r; }   // strict > keeps FIRST max (jnp.argmax)
    if (v2 > bv2) { bv2 = v2; best2 = r; }
  }
  rsel[b * HW + p0 + tid] = best1 | (best2 << 8);
}

// ---------------- stage B: selected correlation conv via MFMA ----------------
// C[o(32), entry(16)] per group; A = generated weights, B = input pixels.

__global__ __launch_bounds__(256) void stageB_kernel(
    const char* __restrict__ inTp, const short* __restrict__ kernA,
    const int* __restrict__ rsel, char* __restrict__ catp) {
  const int id = blockIdx.x;
  const int chunk = id & 7, r = (id >> 3) & 7, b = id >> 6;  // chunk fastest -> XCD affinity
  const int pbase = chunk * 2048;
  __shared__ int lcount;
  __shared__ unsigned short list[4096];
  const int tid = threadIdx.x;
  if (tid == 0) lcount = 0;
  __syncthreads();
  const int* rs = rsel + b * HW + pbase;
  for (int i = tid; i < 2048; i += 256) {
    int v = rs[i];
    if ((v & 255) == r) { int k = atomicAdd(&lcount, 1); list[k] = (unsigned short)i; }
    if ((v >> 8) == r)  { int k = atomicAdd(&lcount, 1); list[k] = (unsigned short)(i | 2048); }
  }
  __syncthreads();
  const int cnt = lcount;
  const int lane = tid & 63, wid = tid >> 6;
  const int l15 = lane & 15, kg = lane >> 4;

  // preload the 18 weight A-fragments (uniform per block)
  short8 aw[18];
  {
    const short* kb = kernA + (size_t)(b * 8 + r) * 18 * 512;
    #pragma unroll
    for (int f = 0; f < 18; ++f)
      aw[f] = *(const short8*)(kb + f * 512 + kg * 128 + l15 * 8);
  }

  for (int g = wid; g * 16 < cnt; g += 4) {
    const int e16 = g * 16 + l15;
    const bool ev = e16 < cnt;
    const int ent = list[ev ? e16 : 0];
    const int p = pbase + (ent & 2047);
    const int which = ent >> 11;
    const int y = p >> 7, x = p & 127;
    const size_t pp = (size_t)(b * PW + y + 1) * PW + (x + 1);
    const char* base = inTp + pp * 64 + kg * 16;
    floatx4 acc0 = {0.f, 0.f, 0.f, 0.f}, acc1 = {0.f, 0.f, 0.f, 0.f};
    #pragma unroll
    for (int t = 0; t < 9; ++t) {
      const int dy = t / 3 - 1, dx = t % 3 - 1;
      const short8 bx = *(const short8*)(base + (dy * PW + dx) * 64);
      acc0 = __builtin_amdgcn_mfma_f32_16x16x32_bf16(aw[t * 2 + 0], bx, acc0, 0, 0, 0);
      acc1 = __builtin_amdgcn_mfma_f32_16x16x32_bf16(aw[t * 2 + 1], bx, acc1, 0, 0, 0);
    }
    if (ev) {
      char* op = catp + pp * 128 + which * 64 + kg * 8;
      uint2 v0, v1;
      v0.x = (unsigned)f2b(acc0[0]) | ((unsigned)f2b(acc0[1]) << 16);
      v0.y = (unsigned)f2b(acc0[2]) | ((unsigned)f2b(acc0[3]) << 16);
      v1.x = (unsigned)f2b(acc1[0]) | ((unsigned)f2b(acc1[1]) << 16);
      v1.y = (unsigned)f2b(acc1[2]) | ((unsigned)f2b(acc1[3]) << 16);
      *(uint2*)op = v0;
      *(uint2*)(op + 32) = v1;
    }
  }
}

// ---------------- stage C: fusion conv via MFMA + bias + residual ----------------
// T1 XCD-chunked swizzle + 3-deep tap pipeline (24 b128 loads in flight/wave).
// launch_bounds(256,3): allow ~160 VGPR without spill (12 waves/CU by VGPR, 3-4 blocks by LDS).

__global__ __launch_bounds__(256, 3) void stageC_kernel(
    const char* __restrict__ catp, const short* __restrict__ wfA,
    const float* __restrict__ b_f, const float* __restrict__ in,
    float* __restrict__ out) {
  __shared__ short lwf[18432];
  const int tid = threadIdx.x;
  {
    const uint4* src = (const uint4*)wfA;
    uint4* dst = (uint4*)lwf;
    #pragma unroll
    for (int i = 0; i < 9; ++i)
      dst[i * 256 + tid] = src[i * 256 + tid];
  }
  __syncthreads();
  const int id = (blockIdx.x & 7) * 128 + (blockIdx.x >> 3);   // T1 XCD swizzle
  const int b = id >> 6, seg = id & 63;
  const int lane = tid & 63, wid = tid >> 6;
  const int l15 = lane & 15, kg = lane >> 4;
  const int pix = seg * 256 + wid * 64 + l15;     // + q*16

  const char* bq[4];
  #pragma unroll
  for (int q = 0; q < 4; ++q) {
    const int p = pix + q * 16;
    const int y = p >> 7, x = p & 127;
    bq[q] = catp + ((size_t)(b * PW + y + 1) * PW + (x + 1)) * 128 + kg * 16;
  }
  floatx4 acc[2][4] = {};
  short8 bxA[8], bxB[8], bxC[8];

#define GOFF(T) (((((T) / 3) - 1) * PW + (((T) % 3) - 1)) * 128)

#define LOADTAP(BUF, T)                                              \
  { _Pragma("unroll")                                                \
    for (int q = 0; q < 4; ++q) {                                    \
      BUF[q * 2 + 0] = *(const short8*)(bq[q] + GOFF(T));            \
      BUF[q * 2 + 1] = *(const short8*)(bq[q] + GOFF(T) + 64);       \
    } }

#define MFMATAP(BUF, T)                                                              \
  { const short8 a00 = *(const short8*)&lwf[(4*(T)+0)*512 + kg*128 + l15*8];          \
    const short8 a01 = *(const short8*)&lwf[(4*(T)+1)*512 + kg*128 + l15*8];          \
    const short8 a10 = *(const short8*)&lwf[(4*(T)+2)*512 + kg*128 + l15*8];          \
    const short8 a11 = *(const short8*)&lwf[(4*(T)+3)*512 + kg*128 + l15*8];          \
    _Pragma("unroll")                                                                 \
    for (int q = 0; q < 4; ++q) {                                                     \
      acc[0][q] = __builtin_amdgcn_mfma_f32_16x16x32_bf16(a00, BUF[q*2+0], acc[0][q], 0, 0, 0); \
      acc[1][q] = __builtin_amdgcn_mfma_f32_16x16x32_bf16(a01, BUF[q*2+0], acc[1][q], 0, 0, 0); \
      acc[0][q] = __builtin_amdgcn_mfma_f32_16x16x32_bf16(a10, BUF[q*2+1], acc[0][q], 0, 0, 0); \
      acc[1][q] = __builtin_amdgcn_mfma_f32_16x16x32_bf16(a11, BUF[q*2+1], acc[1][q], 0, 0, 0); \
    } }

  LOADTAP(bxA, 0)
  LOADTAP(bxB, 1)
  LOADTAP(bxC, 2)
  MFMATAP(bxA, 0)  LOADTAP(bxA, 3)
  MFMATAP(bxB, 1)  LOADTAP(bxB, 4)
  MFMATAP(bxC, 2)  LOADTAP(bxC, 5)
  MFMATAP(bxA, 3)  LOADTAP(bxA, 6)
  MFMATAP(bxB, 4)  LOADTAP(bxB, 7)
  MFMATAP(bxC, 5)  LOADTAP(bxC, 8)
  MFMATAP(bxA, 6)
  MFMATAP(bxB, 7)
  MFMATAP(bxC, 8)
#undef LOADTAP
#undef MFMATAP
#undef GOFF

  #pragma unroll
  for (int h = 0; h < 2; ++h) {
    const int o0 = h * 16 + kg * 4;
    #pragma unroll
    for (int q = 0; q < 4; ++q) {
      const int p = pix + q * 16;
      #pragma unroll
      for (int reg = 0; reg < 4; ++reg) {
        const size_t oi = (size_t)(b * 32 + o0 + reg) * HW + p;
        out[oi] = acc[h][q][reg] + b_f[o0 + reg] + in[oi];
      }
    }
  }
}

// ---------------- launcher ----------------

extern "C" void kernel_launch(void* const* d_in, const int* in_sizes, int n_in,
                              void* d_out, int out_size, void* d_ws, size_t ws_size,
                              hipStream_t stream) {
  const float* input  = (const float*)d_in[0];
  const float* guide  = (const float*)d_in[1];
  const float* w1     = (const float*)d_in[2];
  const float* b1     = (const float*)d_in[3];
  const float* w2     = (const float*)d_in[4];
  const float* b2     = (const float*)d_in[5];
  const float* w_spa  = (const float*)d_in[6];
  const float* b_spa  = (const float*)d_in[7];
  const float* w_spec = (const float*)d_in[8];
  const float* b_spec = (const float*)d_in[9];
  const float* w_f    = (const float*)d_in[10];
  const float* b_f    = (const float*)d_in[11];
  float* out = (float*)d_out;

  char* ws = (char*)d_ws;
  float* poolsum = (float*)(ws + OFF_POOLED);
  float* g      = (float*)(ws + OFF_G);
  short* kernA  = (short*)(ws + OFF_KERNA);
  short* wfA    = (short*)(ws + OFF_WFA);
  int*   rsel   = (int*)(ws + OFF_RSEL);
  uint4* inTp   = (uint4*)(ws + OFF_INTP);
  char*  catp   = (char*)(ws + OFF_CATP);

  wf_kernel<<<72, 256, 0, stream>>>(w_f, wfA, poolsum);
  tr_kernel<<<Bn * 256, 256, 0, stream>>>(input, inTp, poolsum);
  g_kernel<<<(Bn * 64 * 9 + 255) / 256, 256, 0, stream>>>(poolsum, w1, b1, g);
  kern_kernel<<<Bn * 8 * 9 * 1024 / 256, 256, 0, stream>>>(g, w2, b2, kernA);
  rsel_kernel<<<Bn * HW / 256, 256, 0, stream>>>(guide, w_spa, b_spa, w_spec, b_spec,
                                                 rsel, inTp, (uint4*)catp);
  stageB_kernel<<<1024, 256, 0, stream>>>((const char*)inTp, kernA, rsel, catp);
  stageC_kernel<<<1024, 256, 0, stream>>>(catp, wfA, b_f, input, out);
}